// Round 15
// baseline (228.077 us; speedup 1.0000x reference)
//
#include <hip/hip_runtime.h>
#include <hip/hip_fp16.h>

#define N_NODES 50000
#define N_EDGES 250000
#define N_GRAPHS 512
#define F_IN 32
#define F_EDGE 16
#define LATENT 32
#define EMBED 128
#define E_BLK 256
#define N_EBLK ((N_EDGES + E_BLK - 1) / E_BLK)  // 977
#define KW 1056                                  // W2T row length: 1024 + 32 (b2 fold)
#define HS_STRIDE 36                             // Hs row stride in USHORTS (72B rows)

typedef unsigned short ushort;
typedef unsigned int uint;
typedef _Float16 half8v __attribute__((ext_vector_type(8)));
typedef _Float16 half2v __attribute__((ext_vector_type(2)));
typedef __attribute__((ext_vector_type(4))) float f32x4;

union UH8 { half8v h8; half2v h2[4]; ushort u[8]; uint q[4]; };
union UH2 { half2v h2; uint q; };

__device__ inline ushort f2h_bits(float f) {
    _Float16 h = (_Float16)f;
    return *reinterpret_cast<ushort*>(&h);
}

// ---------------- prep: zero deg/pool/pcnt + W2T(f16) [32 l][1056 kk] ----------------
// kk < 1024:  W2T[l][kk] = W2.flat[kk*32 + l]
// kk >= 1024: W2T[l][1024+f] = b2[f*32 + l]    (b2 folded; paired with h == 1)
__global__ void prep_kernel(const float* __restrict__ W2, const float* __restrict__ b2,
                            ushort* __restrict__ W2T, int* __restrict__ deg,
                            float* __restrict__ pool, float* __restrict__ pcnt) {
    int i = blockIdx.x * blockDim.x + threadIdx.x;
    if (i < N_NODES) deg[i] = 0;
    if (i < 32 * 1024) {
        int kk = i >> 5, l = i & 31;
        W2T[l * KW + kk] = f2h_bits(W2[i]);   // coalesced read
    }
    if (i < 1024) {
        int f = i >> 5, l = i & 31;
        W2T[l * KW + 1024 + f] = f2h_bits(b2[i]);
    }
    if (i < N_GRAPHS * LATENT) pool[i] = 0.f;
    if (i < N_GRAPHS) pcnt[i] = 0.f;
}

// ---------------- per-dst-node CSR build ----------------
__global__ void hist_kernel(const int* __restrict__ ei, int* __restrict__ deg) {
    int e = blockIdx.x * blockDim.x + threadIdx.x;
    if (e < N_EDGES) atomicAdd(&deg[ei[N_EDGES + e]], 1);
}

// two-pass register scan: 1024 threads x CH=49 nodes each (no large register arrays)
__global__ __launch_bounds__(1024) void scan_kernel(const int* __restrict__ deg,
                                                    int* __restrict__ off,
                                                    int* __restrict__ cursor) {
    __shared__ int wsum[16];
    const int CH = 49;  // 1024*49 = 50176 >= N_NODES
    int t = threadIdx.x;
    int s = t * CH;
    int sum = 0;
    for (int i = 0; i < CH; ++i) {
        int idx = s + i;
        sum += (idx < N_NODES) ? deg[idx] : 0;
    }
    int lane = t & 63, wid = t >> 6;
    int inc = sum;
    #pragma unroll
    for (int d = 1; d < 64; d <<= 1) {
        int o = __shfl_up(inc, d);
        if (lane >= d) inc += o;
    }
    if (lane == 63) wsum[wid] = inc;
    __syncthreads();
    if (t < 16) {
        int wv = wsum[t];
        int winc = wv;
        #pragma unroll
        for (int d = 1; d < 16; d <<= 1) {
            int o = __shfl_up(winc, d);
            if (t >= d) winc += o;
        }
        wsum[t] = winc - wv;  // exclusive wave offset
    }
    __syncthreads();
    int run = wsum[wid] + (inc - sum);  // exclusive prefix for this thread
    for (int i = 0; i < CH; ++i) {
        int idx = s + i;
        if (idx < N_NODES) {
            int d = deg[idx];
            off[idx] = run; cursor[idx] = run; run += d;
        }
    }
    if (t == 1023) off[N_NODES] = run;  // == N_EDGES
}

__global__ void scatter_kernel(const int* __restrict__ ei, int* __restrict__ cursor,
                               int* __restrict__ csr) {
    int e = blockIdx.x * blockDim.x + threadIdx.x;
    if (e < N_EDGES) {
        int p = atomicAdd(&cursor[ei[N_EDGES + e]], 1);
        csr[p] = e;
    }
}

// ---------------- edge kernel: MSG[E x 32] = G[E x 1056] @ W2T^T  (f16 MFMA) ----------------
// Identical to the proven R14 pipeline EXCEPT the tail: plain coalesced __half2 stores
// to per-edge msg rows (no atomics, no collisions).
__global__ __launch_bounds__(512) void edge_mfma_kernel(
    const float* __restrict__ x, const int* __restrict__ ei,
    const float* __restrict__ ea, const float* __restrict__ W1,
    const float* __restrict__ b1, const ushort* __restrict__ W2T,
    __half* __restrict__ msg)
{
    __shared__ __attribute__((aligned(16))) ushort Hs[E_BLK * HS_STRIDE]; // h f16, 18KB
    __shared__ __attribute__((aligned(16))) ushort W2q[32 * 256];         // 16KB; swz ^((j&7)<<4)

    const int t = threadIdx.x;
    const int e0 = blockIdx.x * E_BLK;
    const int wv = t >> 6, lane = t & 63;
    const int g = lane >> 4, j16 = lane & 15;

    // ---- H = relu(ea @ W1 + b1) via K-padded f16 MFMA (f>=16 lanes hold zeros)
    UH8 bw[2];
    #pragma unroll
    for (int nt = 0; nt < 2; ++nt) {
        #pragma unroll
        for (int b = 0; b < 8; ++b) {
            float w = (g < 2) ? W1[(8 * g + b) * LATENT + nt * 16 + j16] : 0.f;
            bw[nt].u[b] = f2h_bits(w);
        }
    }
    float b1v[2] = { b1[j16], b1[16 + j16] };

    #pragma unroll
    for (int mt = 0; mt < 2; ++mt) {
        int mtg = 2 * wv + mt;               // 0..15
        int rowA = mtg * 16 + j16;
        int e = e0 + rowA; if (e >= N_EDGES) e = N_EDGES - 1;
        UH8 ae;
        if (g < 2) {
            const float4* p = (const float4*)(ea + (size_t)e * F_EDGE + 8 * g);
            float4 va = p[0], vb = p[1];
            ae.u[0] = f2h_bits(va.x); ae.u[1] = f2h_bits(va.y);
            ae.u[2] = f2h_bits(va.z); ae.u[3] = f2h_bits(va.w);
            ae.u[4] = f2h_bits(vb.x); ae.u[5] = f2h_bits(vb.y);
            ae.u[6] = f2h_bits(vb.z); ae.u[7] = f2h_bits(vb.w);
        } else {
            ae.q[0] = 0; ae.q[1] = 0; ae.q[2] = 0; ae.q[3] = 0;
        }
        #pragma unroll
        for (int nt = 0; nt < 2; ++nt) {
            f32x4 hacc = (f32x4){0.f, 0.f, 0.f, 0.f};
            hacc = __builtin_amdgcn_mfma_f32_16x16x32_f16(ae.h8, bw[nt].h8, hacc, 0, 0, 0);
            #pragma unroll
            for (int v = 0; v < 4; ++v) {
                int rowD = mtg * 16 + 4 * g + v;
                int col = nt * 16 + j16;
                float hval = fmaxf(hacc[v] + b1v[nt], 0.f);
                Hs[rowD * HS_STRIDE + col] = f2h_bits(hval);   // intra-wave rows only
            }
        }
    }

    // ---- x fragments read directly as f32, converted once per M-tile
    f32x4 acc[2][2];
    #pragma unroll
    for (int a = 0; a < 2; ++a)
        #pragma unroll
        for (int b = 0; b < 2; ++b) acc[a][b] = (f32x4){0.f, 0.f, 0.f, 0.f};

    UH8 xf[2];
    int myrow[2];
    #pragma unroll
    for (int mt = 0; mt < 2; ++mt) {
        int row = (2 * wv + mt) * 16 + j16;
        myrow[mt] = row;
        int e = e0 + row; if (e >= N_EDGES) e = N_EDGES - 1;
        int src = ei[e];
        const float4* p = (const float4*)(x + (size_t)src * F_IN + 8 * g);
        float4 va = p[0], vb = p[1];
        xf[mt].u[0] = f2h_bits(va.x); xf[mt].u[1] = f2h_bits(va.y);
        xf[mt].u[2] = f2h_bits(va.z); xf[mt].u[3] = f2h_bits(va.w);
        xf[mt].u[4] = f2h_bits(vb.x); xf[mt].u[5] = f2h_bits(vb.y);
        xf[mt].u[6] = f2h_bits(vb.z); xf[mt].u[7] = f2h_bits(vb.w);
    }

    // ---- b2-extension K-step: A = x fragment directly (h == 1)
    {
        UH8 bx0, bx1;
        *(uint4*)bx0.q = *(const uint4*)(W2T + (size_t)j16 * KW + 1024 + 8 * g);
        *(uint4*)bx1.q = *(const uint4*)(W2T + (size_t)(16 + j16) * KW + 1024 + 8 * g);
        #pragma unroll
        for (int mt = 0; mt < 2; ++mt) {
            acc[mt][0] = __builtin_amdgcn_mfma_f32_16x16x32_f16(xf[mt].h8, bx0.h8, acc[mt][0], 0, 0, 0);
            acc[mt][1] = __builtin_amdgcn_mfma_f32_16x16x32_f16(xf[mt].h8, bx1.h8, acc[mt][1], 0, 0, 0);
        }
    }

    // ---- K loop: 4 quarters of 256 kk, W2T staged per quarter (XOR-swizzled)
    for (int q = 0; q < 4; ++q) {
        if (q) __syncthreads();
        #pragma unroll
        for (int c = 0; c < 2; ++c) {
            int ch = c * 512 + t;           // 1024 uint4 = 16KB staged by 512 threads
            int lbyte = ch * 16;
            int jrow = lbyte >> 9;
            int off = lbyte & 511;
            uint4 val = *(const uint4*)((const char*)W2T + (size_t)jrow * (KW * 2) + q * 512 + off);
            *(uint4*)((char*)W2q + jrow * 512 + (off ^ ((jrow & 7) << 4))) = val;
        }
        __syncthreads();

        uint hbp[2][8];
        #pragma unroll
        for (int mt = 0; mt < 2; ++mt) {
            const ushort* hp = Hs + myrow[mt] * HS_STRIDE + q * 8;
            uint2 ra = *(const uint2*)hp;
            uint2 rb = *(const uint2*)(hp + 4);
            uint raw[4] = { ra.x, ra.y, rb.x, rb.y };
            #pragma unroll
            for (int i = 0; i < 4; ++i) {
                uint u = raw[i];
                hbp[mt][2 * i]     = (u & 0xFFFFu) * 0x10001u;
                hbp[mt][2 * i + 1] = (u >> 16) * 0x10001u;
            }
        }

        #pragma unroll
        for (int kst = 0; kst < 8; ++kst) {
            int kb = kst * 64 + g * 16;
            UH8 bf0, bf1;
            *(uint4*)bf0.q = *(const uint4*)((const char*)W2q + j16 * 512 + (kb ^ ((j16 & 7) << 4)));
            *(uint4*)bf1.q = *(const uint4*)((const char*)W2q + (16 + j16) * 512 + (kb ^ ((j16 & 7) << 4)));
            #pragma unroll
            for (int mt = 0; mt < 2; ++mt) {
                UH2 h2; h2.q = hbp[mt][kst];
                UH8 af;
                #pragma unroll
                for (int p = 0; p < 4; ++p) af.h2[p] = h2.h2 * xf[mt].h2[p];  // v_pk_mul_f16
                acc[mt][0] = __builtin_amdgcn_mfma_f32_16x16x32_f16(af.h8, bf0.h8, acc[mt][0], 0, 0, 0);
                acc[mt][1] = __builtin_amdgcn_mfma_f32_16x16x32_f16(af.h8, bf1.h8, acc[mt][1], 0, 0, 0);
            }
        }
    }

    // ---- store messages to msg[e][32]: plain coalesced __half2 stores, no atomics
    const int odd = j16 & 1;
    #pragma unroll
    for (int mt = 0; mt < 2; ++mt) {
        int rowb = (2 * wv + mt) * 16 + 4 * g;
        #pragma unroll
        for (int v = 0; v < 4; ++v) {
            int e = e0 + rowb + v;
            float a0 = acc[mt][0][v], a1 = acc[mt][1][v];
            float p0 = __shfl_xor(a0, 1);
            float p1 = __shfl_xor(a1, 1);
            if (e < N_EDGES) {
                __half2 hv = odd ? __floats2half2_rn(p1, a1) : __floats2half2_rn(a0, p0);
                int col = odd ? (15 + j16) : j16;
                *(__half2*)(msg + (size_t)e * LATENT + col) = hv;
            }
        }
    }
}

// ---------------- gather + node update + global mean pool ----------------
// Lane l owns column l; each 32-lane group walks VN consecutive nodes; per node, sums
// its in-edges' msg rows via CSR (each row = one 64B L2-resident line), then the
// x@root + relu + sorted-batch pooled accumulation (proven nodepool logic).
#define VN 8
__global__ __launch_bounds__(256) void gather_pool_kernel(
    const float* __restrict__ x, const __half* __restrict__ msg,
    const int* __restrict__ off, const int* __restrict__ csr,
    const float* __restrict__ root, const float* __restrict__ cbias,
    const int* __restrict__ batch, float* __restrict__ pool,
    float* __restrict__ pcnt)
{
    int t = threadIdx.x;
    int l = t & 31;
    int stripe = t >> 5;  // 0..7
    int v0 = (blockIdx.x * 8 + stripe) * VN;
    float rc[F_IN];
    #pragma unroll
    for (int f = 0; f < F_IN; ++f) rc[f] = root[f * LATENT + l];
    float cbl = cbias[l];

    float sum = 0.f, cnt = 0.f;
    int gcur = -1;
    for (int i = 0; i < VN; ++i) {
        int v = v0 + i;
        if (v >= N_NODES) break;
        int g = batch[v];
        if (g != gcur) {
            if (gcur >= 0) {
                atomicAdd(&pool[gcur * LATENT + l], sum);
                if (l == 0) atomicAdd(&pcnt[gcur], cnt);
            }
            gcur = g; sum = 0.f; cnt = 0.f;
        }
        float xv = x[(size_t)v * F_IN + l];     // coalesced
        float a = cbl;
        int p0 = off[v], p1 = off[v + 1];
        for (int p = p0; p < p1; ++p) {
            int e = csr[p];                     // wave-uniform broadcast
            a += __half2float(msg[(size_t)e * LATENT + l]);  // one 64B line / edge
        }
        #pragma unroll
        for (int f = 0; f < F_IN; ++f) {
            float xfv = __shfl(xv, (t & 32) | f);
            a += xfv * rc[f];
        }
        sum += fmaxf(a, 0.f);
        cnt += 1.f;
    }
    if (gcur >= 0) {
        atomicAdd(&pool[gcur * LATENT + l], sum);
        if (l == 0) atomicAdd(&pcnt[gcur], cnt);
    }
}

// ---------------- final FC ----------------
__global__ void final_kernel(const float* __restrict__ pool, const float* __restrict__ pcnt,
                             const float* __restrict__ fcw, const float* __restrict__ fcb,
                             float* __restrict__ out)
{
    int t = blockIdx.x * blockDim.x + threadIdx.x;
    int gr = t >> 7, j = t & 127;
    if (gr >= N_GRAPHS) return;
    float inv = 1.0f / fmaxf(pcnt[gr], 1.0f);
    float o = fcb[j];
    #pragma unroll 8
    for (int l = 0; l < LATENT; ++l) {
        float pv = fmaxf(pool[gr * LATENT + l] * inv, 0.0f);
        o += pv * fcw[l * EMBED + j];
    }
    out[gr * EMBED + j] = o;
}

extern "C" void kernel_launch(void* const* d_in, const int* in_sizes, int n_in,
                              void* d_out, int out_size, void* d_ws, size_t ws_size,
                              hipStream_t stream)
{
    const float* x     = (const float*)d_in[0];
    const int*   ei    = (const int*)d_in[1];
    const float* ea    = (const float*)d_in[2];
    const int*   batch = (const int*)d_in[3];
    const float* W1    = (const float*)d_in[4];
    const float* b1    = (const float*)d_in[5];
    const float* W2    = (const float*)d_in[6];
    const float* b2    = (const float*)d_in[7];
    const float* root  = (const float*)d_in[8];
    const float* cb    = (const float*)d_in[9];
    const float* fcw   = (const float*)d_in[10];
    const float* fcb   = (const float*)d_in[11];
    float* out = (float*)d_out;

    char* w = (char*)d_ws;
    auto alloc = [&](size_t bytes) {
        char* p = w;
        w += (bytes + 255) & ~size_t(255);
        return p;
    };
    ushort* W2T    = (ushort*)alloc((size_t)32 * KW * 2);
    __half* msg    = (__half*)alloc((size_t)N_EDGES * LATENT * 2);   // 16 MB
    int*    deg    = (int*)alloc(N_NODES * 4);
    int*    off    = (int*)alloc((N_NODES + 1) * 4);
    int*    cursor = (int*)alloc(N_NODES * 4);
    int*    csr    = (int*)alloc(N_EDGES * 4);
    float*  pool   = (float*)alloc(N_GRAPHS * LATENT * 4);
    float*  pcnt   = (float*)alloc(N_GRAPHS * 4);

    prep_kernel<<<196, 256, 0, stream>>>(W2, b2, W2T, deg, pool, pcnt);
    hist_kernel<<<(N_EDGES + 255) / 256, 256, 0, stream>>>(ei, deg);
    scan_kernel<<<1, 1024, 0, stream>>>(deg, off, cursor);
    scatter_kernel<<<(N_EDGES + 255) / 256, 256, 0, stream>>>(ei, cursor, csr);
    edge_mfma_kernel<<<N_EBLK, 512, 0, stream>>>(x, ei, ea, W1, b1, W2T, msg);
    gather_pool_kernel<<<(N_NODES + 8 * VN - 1) / (8 * VN), 256, 0, stream>>>(
        x, msg, off, csr, root, cb, batch, pool, pcnt);
    final_kernel<<<(N_GRAPHS * EMBED + 255) / 256, 256, 0, stream>>>(pool, pcnt, fcw, fcb, out);
}

// Round 16
// 112.818 us; speedup vs baseline: 2.0216x; 2.0216x over previous
//
#include <hip/hip_runtime.h>
#include <hip/hip_fp16.h>

#define N_NODES 50000
#define N_EDGES 250000
#define N_GRAPHS 512
#define F_IN 32
#define F_EDGE 16
#define LATENT 32
#define EMBED 128
#define E_BLK 256
#define N_EBLK ((N_EDGES + E_BLK - 1) / E_BLK)  // 977
#define KW 1056                                  // W2T row length: 1024 + 32 (b2 fold)
#define HS_STRIDE 36                             // Hs row stride in USHORTS (72B rows)
#define SCAN_B ((N_NODES + 255) / 256)           // 196 scan blocks

typedef unsigned short ushort;
typedef unsigned int uint;
typedef _Float16 half8v __attribute__((ext_vector_type(8)));
typedef _Float16 half2v __attribute__((ext_vector_type(2)));
typedef __attribute__((ext_vector_type(4))) float f32x4;

union UH8 { half8v h8; half2v h2[4]; ushort u[8]; uint q[4]; };
union UH2 { half2v h2; uint q; };

__device__ inline ushort f2h_bits(float f) {
    _Float16 h = (_Float16)f;
    return *reinterpret_cast<ushort*>(&h);
}

// ---------------- prep: zero deg/pool/pcnt + W2T(f16) [32 l][1056 kk] ----------------
__global__ void prep_kernel(const float* __restrict__ W2, const float* __restrict__ b2,
                            ushort* __restrict__ W2T, int* __restrict__ deg,
                            float* __restrict__ pool, float* __restrict__ pcnt) {
    int i = blockIdx.x * blockDim.x + threadIdx.x;
    if (i < N_NODES) deg[i] = 0;
    if (i < 32 * 1024) {
        int kk = i >> 5, l = i & 31;
        W2T[l * KW + kk] = f2h_bits(W2[i]);   // coalesced read
    }
    if (i < 1024) {
        int f = i >> 5, l = i & 31;
        W2T[l * KW + 1024 + f] = f2h_bits(b2[i]);
    }
    if (i < N_GRAPHS * LATENT) pool[i] = 0.f;
    if (i < N_GRAPHS) pcnt[i] = 0.f;
}

// ---------------- per-dst-node CSR build (hierarchical coalesced scan) ----------------
__global__ void hist_kernel(const int* __restrict__ ei, int* __restrict__ deg) {
    int e = blockIdx.x * blockDim.x + threadIdx.x;
    if (e < N_EDGES) atomicAdd(&deg[ei[N_EDGES + e]], 1);
}

// scan1: per-block exclusive scan of 256 deg values; off[i] = in-block exclusive; bsum[b] = total
__global__ __launch_bounds__(256) void scan1_kernel(const int* __restrict__ deg,
                                                    int* __restrict__ off,
                                                    int* __restrict__ bsum) {
    __shared__ int ws[4];
    int t = threadIdx.x;
    int i = blockIdx.x * 256 + t;
    int d = (i < N_NODES) ? deg[i] : 0;
    int lane = t & 63, wid = t >> 6;
    int inc = d;
    #pragma unroll
    for (int s = 1; s < 64; s <<= 1) { int o = __shfl_up(inc, s); if (lane >= s) inc += o; }
    if (lane == 63) ws[wid] = inc;
    __syncthreads();
    if (t < 4) {
        int w = ws[t]; int wi = w;
        #pragma unroll
        for (int s = 1; s < 4; s <<= 1) { int o = __shfl_up(wi, s); if (t >= s) wi += o; }
        ws[t] = wi - w;
    }
    __syncthreads();
    int ex = ws[wid] + inc - d;
    if (i < N_NODES) off[i] = ex;
    if (t == 255) bsum[blockIdx.x] = ex + d;
}

// scan2: one block scans the 196 block totals
__global__ __launch_bounds__(256) void scan2_kernel(int* __restrict__ bsum) {
    __shared__ int ws[4];
    int t = threadIdx.x;
    int d = (t < SCAN_B) ? bsum[t] : 0;
    int lane = t & 63, wid = t >> 6;
    int inc = d;
    #pragma unroll
    for (int s = 1; s < 64; s <<= 1) { int o = __shfl_up(inc, s); if (lane >= s) inc += o; }
    if (lane == 63) ws[wid] = inc;
    __syncthreads();
    if (t < 4) {
        int w = ws[t]; int wi = w;
        #pragma unroll
        for (int s = 1; s < 4; s <<= 1) { int o = __shfl_up(wi, s); if (t >= s) wi += o; }
        ws[t] = wi - w;
    }
    __syncthreads();
    if (t < SCAN_B) bsum[t] = ws[wid] + inc - d;   // in-place -> exclusive block offsets
}

// scan3: finalize off/cursor
__global__ void scan3_kernel(const int* __restrict__ bsum, int* __restrict__ off,
                             int* __restrict__ cursor) {
    int i = blockIdx.x * 256 + threadIdx.x;
    if (i < N_NODES) {
        int o = off[i] + bsum[blockIdx.x];
        off[i] = o; cursor[i] = o;
    }
    if (i == 0) off[N_NODES] = N_EDGES;
}

__global__ void scatter_kernel(const int* __restrict__ ei, int* __restrict__ cursor,
                               int* __restrict__ csr) {
    int e = blockIdx.x * blockDim.x + threadIdx.x;
    if (e < N_EDGES) {
        int p = atomicAdd(&cursor[ei[N_EDGES + e]], 1);
        csr[p] = e;
    }
}

// ---------------- edge kernel: MSG[E x 32] = G[E x 1056] @ W2T^T  (f16 MFMA) ----------------
// Proven R14 pipeline; tail = plain coalesced __half2 stores to per-edge msg rows (NO atomics).
__global__ __launch_bounds__(512) void edge_mfma_kernel(
    const float* __restrict__ x, const int* __restrict__ ei,
    const float* __restrict__ ea, const float* __restrict__ W1,
    const float* __restrict__ b1, const ushort* __restrict__ W2T,
    __half* __restrict__ msg)
{
    __shared__ __attribute__((aligned(16))) ushort Hs[E_BLK * HS_STRIDE]; // h f16, 18KB
    __shared__ __attribute__((aligned(16))) ushort W2q[32 * 256];         // 16KB; swz ^((j&7)<<4)

    const int t = threadIdx.x;
    const int e0 = blockIdx.x * E_BLK;
    const int wv = t >> 6, lane = t & 63;
    const int g = lane >> 4, j16 = lane & 15;

    UH8 bw[2];
    #pragma unroll
    for (int nt = 0; nt < 2; ++nt) {
        #pragma unroll
        for (int b = 0; b < 8; ++b) {
            float w = (g < 2) ? W1[(8 * g + b) * LATENT + nt * 16 + j16] : 0.f;
            bw[nt].u[b] = f2h_bits(w);
        }
    }
    float b1v[2] = { b1[j16], b1[16 + j16] };

    #pragma unroll
    for (int mt = 0; mt < 2; ++mt) {
        int mtg = 2 * wv + mt;
        int rowA = mtg * 16 + j16;
        int e = e0 + rowA; if (e >= N_EDGES) e = N_EDGES - 1;
        UH8 ae;
        if (g < 2) {
            const float4* p = (const float4*)(ea + (size_t)e * F_EDGE + 8 * g);
            float4 va = p[0], vb = p[1];
            ae.u[0] = f2h_bits(va.x); ae.u[1] = f2h_bits(va.y);
            ae.u[2] = f2h_bits(va.z); ae.u[3] = f2h_bits(va.w);
            ae.u[4] = f2h_bits(vb.x); ae.u[5] = f2h_bits(vb.y);
            ae.u[6] = f2h_bits(vb.z); ae.u[7] = f2h_bits(vb.w);
        } else {
            ae.q[0] = 0; ae.q[1] = 0; ae.q[2] = 0; ae.q[3] = 0;
        }
        #pragma unroll
        for (int nt = 0; nt < 2; ++nt) {
            f32x4 hacc = (f32x4){0.f, 0.f, 0.f, 0.f};
            hacc = __builtin_amdgcn_mfma_f32_16x16x32_f16(ae.h8, bw[nt].h8, hacc, 0, 0, 0);
            #pragma unroll
            for (int v = 0; v < 4; ++v) {
                int rowD = mtg * 16 + 4 * g + v;
                int col = nt * 16 + j16;
                float hval = fmaxf(hacc[v] + b1v[nt], 0.f);
                Hs[rowD * HS_STRIDE + col] = f2h_bits(hval);
            }
        }
    }

    f32x4 acc[2][2];
    #pragma unroll
    for (int a = 0; a < 2; ++a)
        #pragma unroll
        for (int b = 0; b < 2; ++b) acc[a][b] = (f32x4){0.f, 0.f, 0.f, 0.f};

    UH8 xf[2];
    int myrow[2];
    #pragma unroll
    for (int mt = 0; mt < 2; ++mt) {
        int row = (2 * wv + mt) * 16 + j16;
        myrow[mt] = row;
        int e = e0 + row; if (e >= N_EDGES) e = N_EDGES - 1;
        int src = ei[e];
        const float4* p = (const float4*)(x + (size_t)src * F_IN + 8 * g);
        float4 va = p[0], vb = p[1];
        xf[mt].u[0] = f2h_bits(va.x); xf[mt].u[1] = f2h_bits(va.y);
        xf[mt].u[2] = f2h_bits(va.z); xf[mt].u[3] = f2h_bits(va.w);
        xf[mt].u[4] = f2h_bits(vb.x); xf[mt].u[5] = f2h_bits(vb.y);
        xf[mt].u[6] = f2h_bits(vb.z); xf[mt].u[7] = f2h_bits(vb.w);
    }

    {
        UH8 bx0, bx1;
        *(uint4*)bx0.q = *(const uint4*)(W2T + (size_t)j16 * KW + 1024 + 8 * g);
        *(uint4*)bx1.q = *(const uint4*)(W2T + (size_t)(16 + j16) * KW + 1024 + 8 * g);
        #pragma unroll
        for (int mt = 0; mt < 2; ++mt) {
            acc[mt][0] = __builtin_amdgcn_mfma_f32_16x16x32_f16(xf[mt].h8, bx0.h8, acc[mt][0], 0, 0, 0);
            acc[mt][1] = __builtin_amdgcn_mfma_f32_16x16x32_f16(xf[mt].h8, bx1.h8, acc[mt][1], 0, 0, 0);
        }
    }

    for (int q = 0; q < 4; ++q) {
        if (q) __syncthreads();
        #pragma unroll
        for (int c = 0; c < 2; ++c) {
            int ch = c * 512 + t;
            int lbyte = ch * 16;
            int jrow = lbyte >> 9;
            int off = lbyte & 511;
            uint4 val = *(const uint4*)((const char*)W2T + (size_t)jrow * (KW * 2) + q * 512 + off);
            *(uint4*)((char*)W2q + jrow * 512 + (off ^ ((jrow & 7) << 4))) = val;
        }
        __syncthreads();

        uint hbp[2][8];
        #pragma unroll
        for (int mt = 0; mt < 2; ++mt) {
            const ushort* hp = Hs + myrow[mt] * HS_STRIDE + q * 8;
            uint2 ra = *(const uint2*)hp;
            uint2 rb = *(const uint2*)(hp + 4);
            uint raw[4] = { ra.x, ra.y, rb.x, rb.y };
            #pragma unroll
            for (int i = 0; i < 4; ++i) {
                uint u = raw[i];
                hbp[mt][2 * i]     = (u & 0xFFFFu) * 0x10001u;
                hbp[mt][2 * i + 1] = (u >> 16) * 0x10001u;
            }
        }

        #pragma unroll
        for (int kst = 0; kst < 8; ++kst) {
            int kb = kst * 64 + g * 16;
            UH8 bf0, bf1;
            *(uint4*)bf0.q = *(const uint4*)((const char*)W2q + j16 * 512 + (kb ^ ((j16 & 7) << 4)));
            *(uint4*)bf1.q = *(const uint4*)((const char*)W2q + (16 + j16) * 512 + (kb ^ ((j16 & 7) << 4)));
            #pragma unroll
            for (int mt = 0; mt < 2; ++mt) {
                UH2 h2; h2.q = hbp[mt][kst];
                UH8 af;
                #pragma unroll
                for (int p = 0; p < 4; ++p) af.h2[p] = h2.h2 * xf[mt].h2[p];
                acc[mt][0] = __builtin_amdgcn_mfma_f32_16x16x32_f16(af.h8, bf0.h8, acc[mt][0], 0, 0, 0);
                acc[mt][1] = __builtin_amdgcn_mfma_f32_16x16x32_f16(af.h8, bf1.h8, acc[mt][1], 0, 0, 0);
            }
        }
    }

    // ---- store messages: plain coalesced __half2 stores, no atomics
    const int odd = j16 & 1;
    #pragma unroll
    for (int mt = 0; mt < 2; ++mt) {
        int rowb = (2 * wv + mt) * 16 + 4 * g;
        #pragma unroll
        for (int v = 0; v < 4; ++v) {
            int e = e0 + rowb + v;
            float a0 = acc[mt][0][v], a1 = acc[mt][1][v];
            float p0 = __shfl_xor(a0, 1);
            float p1 = __shfl_xor(a1, 1);
            if (e < N_EDGES) {
                __half2 hv = odd ? __floats2half2_rn(p1, a1) : __floats2half2_rn(a0, p0);
                int col = odd ? (15 + j16) : j16;
                *(__half2*)(msg + (size_t)e * LATENT + col) = hv;
            }
        }
    }
}

// ---------------- gather + node update + global mean pool ----------------
#define VN 8
__global__ __launch_bounds__(256) void gather_pool_kernel(
    const float* __restrict__ x, const __half* __restrict__ msg,
    const int* __restrict__ off, const int* __restrict__ csr,
    const float* __restrict__ root, const float* __restrict__ cbias,
    const int* __restrict__ batch, float* __restrict__ pool,
    float* __restrict__ pcnt)
{
    int t = threadIdx.x;
    int l = t & 31;
    int stripe = t >> 5;
    int v0 = (blockIdx.x * 8 + stripe) * VN;
    float rc[F_IN];
    #pragma unroll
    for (int f = 0; f < F_IN; ++f) rc[f] = root[f * LATENT + l];
    float cbl = cbias[l];

    float sum = 0.f, cnt = 0.f;
    int gcur = -1;
    for (int i = 0; i < VN; ++i) {
        int v = v0 + i;
        if (v >= N_NODES) break;
        int g = batch[v];
        if (g != gcur) {
            if (gcur >= 0) {
                atomicAdd(&pool[gcur * LATENT + l], sum);
                if (l == 0) atomicAdd(&pcnt[gcur], cnt);
            }
            gcur = g; sum = 0.f; cnt = 0.f;
        }
        float xv = x[(size_t)v * F_IN + l];
        float a = cbl;
        int p0 = off[v], p1 = off[v + 1];
        for (int p = p0; p < p1; ++p) {
            int e = csr[p];
            a += __half2float(msg[(size_t)e * LATENT + l]);  // one 64B line / edge
        }
        #pragma unroll
        for (int f = 0; f < F_IN; ++f) {
            float xfv = __shfl(xv, (t & 32) | f);
            a += xfv * rc[f];
        }
        sum += fmaxf(a, 0.f);
        cnt += 1.f;
    }
    if (gcur >= 0) {
        atomicAdd(&pool[gcur * LATENT + l], sum);
        if (l == 0) atomicAdd(&pcnt[gcur], cnt);
    }
}

// ---------------- final FC ----------------
__global__ void final_kernel(const float* __restrict__ pool, const float* __restrict__ pcnt,
                             const float* __restrict__ fcw, const float* __restrict__ fcb,
                             float* __restrict__ out)
{
    int t = blockIdx.x * blockDim.x + threadIdx.x;
    int gr = t >> 7, j = t & 127;
    if (gr >= N_GRAPHS) return;
    float inv = 1.0f / fmaxf(pcnt[gr], 1.0f);
    float o = fcb[j];
    #pragma unroll 8
    for (int l = 0; l < LATENT; ++l) {
        float pv = fmaxf(pool[gr * LATENT + l] * inv, 0.0f);
        o += pv * fcw[l * EMBED + j];
    }
    out[gr * EMBED + j] = o;
}

extern "C" void kernel_launch(void* const* d_in, const int* in_sizes, int n_in,
                              void* d_out, int out_size, void* d_ws, size_t ws_size,
                              hipStream_t stream)
{
    const float* x     = (const float*)d_in[0];
    const int*   ei    = (const int*)d_in[1];
    const float* ea    = (const float*)d_in[2];
    const int*   batch = (const int*)d_in[3];
    const float* W1    = (const float*)d_in[4];
    const float* b1    = (const float*)d_in[5];
    const float* W2    = (const float*)d_in[6];
    const float* b2    = (const float*)d_in[7];
    const float* root  = (const float*)d_in[8];
    const float* cb    = (const float*)d_in[9];
    const float* fcw   = (const float*)d_in[10];
    const float* fcb   = (const float*)d_in[11];
    float* out = (float*)d_out;

    char* w = (char*)d_ws;
    auto alloc = [&](size_t bytes) {
        char* p = w;
        w += (bytes + 255) & ~size_t(255);
        return p;
    };
    ushort* W2T    = (ushort*)alloc((size_t)32 * KW * 2);
    __half* msg    = (__half*)alloc((size_t)N_EDGES * LATENT * 2);   // 16 MB
    int*    deg    = (int*)alloc(N_NODES * 4);
    int*    off    = (int*)alloc((N_NODES + 1) * 4);
    int*    cursor = (int*)alloc(N_NODES * 4);
    int*    csr    = (int*)alloc(N_EDGES * 4);
    int*    bsum   = (int*)alloc(SCAN_B * 4);
    float*  pool   = (float*)alloc(N_GRAPHS * LATENT * 4);
    float*  pcnt   = (float*)alloc(N_GRAPHS * 4);

    prep_kernel<<<196, 256, 0, stream>>>(W2, b2, W2T, deg, pool, pcnt);
    hist_kernel<<<(N_EDGES + 255) / 256, 256, 0, stream>>>(ei, deg);
    scan1_kernel<<<SCAN_B, 256, 0, stream>>>(deg, off, bsum);
    scan2_kernel<<<1, 256, 0, stream>>>(bsum);
    scan3_kernel<<<SCAN_B, 256, 0, stream>>>(bsum, off, cursor);
    scatter_kernel<<<(N_EDGES + 255) / 256, 256, 0, stream>>>(ei, cursor, csr);
    edge_mfma_kernel<<<N_EBLK, 512, 0, stream>>>(x, ei, ea, W1, b1, W2T, msg);
    gather_pool_kernel<<<(N_NODES + 8 * VN - 1) / (8 * VN), 256, 0, stream>>>(
        x, msg, off, csr, root, cb, batch, pool, pcnt);
    final_kernel<<<(N_GRAPHS * EMBED + 255) / 256, 256, 0, stream>>>(pool, pcnt, fcw, fcb, out);
}

// Round 17
// 62.608 us; speedup vs baseline: 3.6429x; 1.8020x over previous
//
#include <hip/hip_runtime.h>
#include <hip/hip_fp16.h>

#define N_NODES 50000
#define N_EDGES 250000
#define N_GRAPHS 512
#define F_IN 32
#define F_EDGE 16
#define LATENT 32
#define EMBED 128
#define E_BLK 256
#define N_EBLK ((N_EDGES + E_BLK - 1) / E_BLK)  // 977
#define KW 1056                                  // W2T row length: 1024 + 32 (b2 fold)
#define HS_STRIDE 36                             // Hs row stride in USHORTS (72B rows)

typedef unsigned short ushort;
typedef unsigned int uint;
typedef _Float16 half8v __attribute__((ext_vector_type(8)));
typedef _Float16 half2v __attribute__((ext_vector_type(2)));
typedef __attribute__((ext_vector_type(4))) float f32x4;

union UH8 { half8v h8; half2v h2[4]; ushort u[8]; uint q[4]; };
union UH2 { half2v h2; uint q; };

__device__ inline ushort f2h_bits(float f) {
    _Float16 h = (_Float16)f;
    return *reinterpret_cast<ushort*>(&h);
}

// ---------------- prep: zero agg(f16)/pool + W2T(f16) [32 l][1056 kk] ----------------
// kk < 1024:  W2T[l][kk] = W2.flat[kk*32 + l]
// kk >= 1024: W2T[l][1024+f] = b2[f*32 + l]    (b2 folded; paired with h == 1)
// GRID: must cover N_NODES*LATENT*2/16 = 200000 threads for the agg zeroing.
__global__ void prep_kernel(const float* __restrict__ W2, const float* __restrict__ b2,
                            ushort* __restrict__ W2T, uint4* __restrict__ aggz,
                            float* __restrict__ pool, float* __restrict__ pcnt) {
    int i = blockIdx.x * blockDim.x + threadIdx.x;
    if (i < (N_NODES * LATENT * 2) / 16) aggz[i] = make_uint4(0u, 0u, 0u, 0u);  // agg f16 zeros
    if (i < 32 * 1024) {
        int kk = i >> 5, l = i & 31;
        W2T[l * KW + kk] = f2h_bits(W2[i]);   // coalesced read
    }
    if (i < 1024) {
        int f = i >> 5, l = i & 31;
        W2T[l * KW + 1024 + f] = f2h_bits(b2[i]);
    }
    if (i < N_GRAPHS * LATENT) pool[i] = 0.f;
    if (i < N_GRAPHS) pcnt[i] = 0.f;
}

// ---------------- edge kernel: MSG[E x 32] = G[E x 1056] @ W2T^T  (f16 MFMA) ----------------
// G[e, k*32+f] = h[e,k] * x[src_e, f]  (k<32) ;  G[e, 1024+f] = x[src_e, f]
// MFMA 16x16x32: A row i = lane&15, k-slot = (lane>>4)*8+b;
//                D col j = lane&15, row i = (lane>>4)*4 + reg.
// 512 threads = 8 waves; each wave owns 2 16-row M-tiles (256 edges/block).
// Hs raw ushort (18KB); W2q staged per quarter (16KB, XOR-swizzled).
// Scatter: packed f16 atomics (global_atomic_pk_add_f16), 2 cols per lane-atomic.
__global__ __launch_bounds__(512) void edge_mfma_kernel(
    const float* __restrict__ x, const int* __restrict__ ei,
    const float* __restrict__ ea, const float* __restrict__ W1,
    const float* __restrict__ b1, const ushort* __restrict__ W2T,
    __half* __restrict__ aggh)
{
    __shared__ __attribute__((aligned(16))) ushort Hs[E_BLK * HS_STRIDE]; // h f16, 18KB
    __shared__ __attribute__((aligned(16))) ushort W2q[32 * 256];         // 16KB; row=j (512B), swz ^((j&7)<<4)

    const int t = threadIdx.x;
    const int e0 = blockIdx.x * E_BLK;
    const int wv = t >> 6, lane = t & 63;
    const int g = lane >> 4, j16 = lane & 15;

    // ---- H = relu(ea @ W1 + b1) via K-padded f16 MFMA (f>=16 lanes hold zeros)
    UH8 bw[2];
    #pragma unroll
    for (int nt = 0; nt < 2; ++nt) {
        #pragma unroll
        for (int b = 0; b < 8; ++b) {
            float w = (g < 2) ? W1[(8 * g + b) * LATENT + nt * 16 + j16] : 0.f;
            bw[nt].u[b] = f2h_bits(w);
        }
    }
    float b1v[2] = { b1[j16], b1[16 + j16] };

    #pragma unroll
    for (int mt = 0; mt < 2; ++mt) {
        int mtg = 2 * wv + mt;               // 0..15
        int rowA = mtg * 16 + j16;
        int e = e0 + rowA; if (e >= N_EDGES) e = N_EDGES - 1;
        UH8 ae;
        if (g < 2) {
            const float4* p = (const float4*)(ea + (size_t)e * F_EDGE + 8 * g);
            float4 va = p[0], vb = p[1];
            ae.u[0] = f2h_bits(va.x); ae.u[1] = f2h_bits(va.y);
            ae.u[2] = f2h_bits(va.z); ae.u[3] = f2h_bits(va.w);
            ae.u[4] = f2h_bits(vb.x); ae.u[5] = f2h_bits(vb.y);
            ae.u[6] = f2h_bits(vb.z); ae.u[7] = f2h_bits(vb.w);
        } else {
            ae.q[0] = 0; ae.q[1] = 0; ae.q[2] = 0; ae.q[3] = 0;
        }
        #pragma unroll
        for (int nt = 0; nt < 2; ++nt) {
            f32x4 hacc = (f32x4){0.f, 0.f, 0.f, 0.f};
            hacc = __builtin_amdgcn_mfma_f32_16x16x32_f16(ae.h8, bw[nt].h8, hacc, 0, 0, 0);
            #pragma unroll
            for (int v = 0; v < 4; ++v) {
                int rowD = mtg * 16 + 4 * g + v;
                int col = nt * 16 + j16;
                float hval = fmaxf(hacc[v] + b1v[nt], 0.f);
                Hs[rowD * HS_STRIDE + col] = f2h_bits(hval);   // intra-wave rows only
            }
        }
    }

    // ---- x fragments read directly as f32, converted once per M-tile
    f32x4 acc[2][2];
    #pragma unroll
    for (int a = 0; a < 2; ++a)
        #pragma unroll
        for (int b = 0; b < 2; ++b) acc[a][b] = (f32x4){0.f, 0.f, 0.f, 0.f};

    UH8 xf[2];
    int myrow[2];
    #pragma unroll
    for (int mt = 0; mt < 2; ++mt) {
        int row = (2 * wv + mt) * 16 + j16;
        myrow[mt] = row;
        int e = e0 + row; if (e >= N_EDGES) e = N_EDGES - 1;
        int src = ei[e];
        const float4* p = (const float4*)(x + (size_t)src * F_IN + 8 * g);
        float4 va = p[0], vb = p[1];
        xf[mt].u[0] = f2h_bits(va.x); xf[mt].u[1] = f2h_bits(va.y);
        xf[mt].u[2] = f2h_bits(va.z); xf[mt].u[3] = f2h_bits(va.w);
        xf[mt].u[4] = f2h_bits(vb.x); xf[mt].u[5] = f2h_bits(vb.y);
        xf[mt].u[6] = f2h_bits(vb.z); xf[mt].u[7] = f2h_bits(vb.w);
    }

    // ---- b2-extension K-step: A = x fragment directly (h == 1)
    {
        UH8 bx0, bx1;
        *(uint4*)bx0.q = *(const uint4*)(W2T + (size_t)j16 * KW + 1024 + 8 * g);
        *(uint4*)bx1.q = *(const uint4*)(W2T + (size_t)(16 + j16) * KW + 1024 + 8 * g);
        #pragma unroll
        for (int mt = 0; mt < 2; ++mt) {
            acc[mt][0] = __builtin_amdgcn_mfma_f32_16x16x32_f16(xf[mt].h8, bx0.h8, acc[mt][0], 0, 0, 0);
            acc[mt][1] = __builtin_amdgcn_mfma_f32_16x16x32_f16(xf[mt].h8, bx1.h8, acc[mt][1], 0, 0, 0);
        }
    }

    // ---- K loop: 4 quarters of 256 kk, W2T staged per quarter (XOR-swizzled)
    for (int q = 0; q < 4; ++q) {
        if (q) __syncthreads();
        #pragma unroll
        for (int c = 0; c < 2; ++c) {
            int ch = c * 512 + t;           // 1024 uint4 = 16KB staged by 512 threads
            int lbyte = ch * 16;
            int jrow = lbyte >> 9;
            int off = lbyte & 511;
            uint4 val = *(const uint4*)((const char*)W2T + (size_t)jrow * (KW * 2) + q * 512 + off);
            *(uint4*)((char*)W2q + jrow * 512 + (off ^ ((jrow & 7) << 4))) = val;
        }
        __syncthreads();

        // fetch this quarter's 8 h-values per M-tile (raw ushort) and repack to {h,h}
        uint hbp[2][8];
        #pragma unroll
        for (int mt = 0; mt < 2; ++mt) {
            const ushort* hp = Hs + myrow[mt] * HS_STRIDE + q * 8;
            uint2 ra = *(const uint2*)hp;
            uint2 rb = *(const uint2*)(hp + 4);
            uint raw[4] = { ra.x, ra.y, rb.x, rb.y };
            #pragma unroll
            for (int i = 0; i < 4; ++i) {
                uint u = raw[i];
                hbp[mt][2 * i]     = (u & 0xFFFFu) * 0x10001u;
                hbp[mt][2 * i + 1] = (u >> 16) * 0x10001u;
            }
        }

        #pragma unroll
        for (int kst = 0; kst < 8; ++kst) {
            int kb = kst * 64 + g * 16;
            UH8 bf0, bf1;
            *(uint4*)bf0.q = *(const uint4*)((const char*)W2q + j16 * 512 + (kb ^ ((j16 & 7) << 4)));
            *(uint4*)bf1.q = *(const uint4*)((const char*)W2q + (16 + j16) * 512 + (kb ^ ((j16 & 7) << 4)));
            #pragma unroll
            for (int mt = 0; mt < 2; ++mt) {
                UH2 h2; h2.q = hbp[mt][kst];
                UH8 af;
                #pragma unroll
                for (int p = 0; p < 4; ++p) af.h2[p] = h2.h2 * xf[mt].h2[p];  // v_pk_mul_f16
                acc[mt][0] = __builtin_amdgcn_mfma_f32_16x16x32_f16(af.h8, bf0.h8, acc[mt][0], 0, 0, 0);
                acc[mt][1] = __builtin_amdgcn_mfma_f32_16x16x32_f16(af.h8, bf1.h8, acc[mt][1], 0, 0, 0);
            }
        }
    }

    // ---- scatter-add to aggh[dst] with packed-f16 atomics (2 cols per lane-atomic)
    const int odd = j16 & 1;
    #pragma unroll
    for (int mt = 0; mt < 2; ++mt) {
        int rowb = (2 * wv + mt) * 16 + 4 * g;
        #pragma unroll
        for (int v = 0; v < 4; ++v) {
            int e = e0 + rowb + v;
            float a0 = acc[mt][0][v], a1 = acc[mt][1][v];
            float p0 = __shfl_xor(a0, 1);
            float p1 = __shfl_xor(a1, 1);
            if (e < N_EDGES) {
                int dst = ei[N_EDGES + e];
                __half2 hv = odd ? __floats2half2_rn(p1, a1) : __floats2half2_rn(a0, p0);
                int col = odd ? (15 + j16) : j16;
                unsafeAtomicAdd((__half2*)(aggh + (size_t)dst * LATENT + col), hv);
            }
        }
    }
}

// ---------------- node update + global mean pool ----------------
// Lane l owns column l; each 32-lane group walks VN consecutive nodes with a running
// per-graph partial sum (batch sorted -> ~1 atomic flush per graph-run per stripe).
#define VN 8
__global__ __launch_bounds__(256) void nodepool_kernel(
    const float* __restrict__ x, const __half* __restrict__ aggh,
    const float* __restrict__ root, const float* __restrict__ cbias,
    const int* __restrict__ batch, float* __restrict__ pool,
    float* __restrict__ pcnt)
{
    int t = threadIdx.x;
    int l = t & 31;
    int stripe = t >> 5;  // 0..7
    int v0 = (blockIdx.x * 8 + stripe) * VN;
    float rc[F_IN];
    #pragma unroll
    for (int f = 0; f < F_IN; ++f) rc[f] = root[f * LATENT + l];
    float cbl = cbias[l];

    float sum = 0.f, cnt = 0.f;
    int gcur = -1;
    for (int i = 0; i < VN; ++i) {
        int v = v0 + i;
        if (v >= N_NODES) break;
        int g = batch[v];
        if (g != gcur) {
            if (gcur >= 0) {
                atomicAdd(&pool[gcur * LATENT + l], sum);
                if (l == 0) atomicAdd(&pcnt[gcur], cnt);
            }
            gcur = g; sum = 0.f; cnt = 0.f;
        }
        float xv = x[(size_t)v * F_IN + l];     // coalesced
        float a = __half2float(aggh[(size_t)v * LATENT + l]) + cbl;
        #pragma unroll
        for (int f = 0; f < F_IN; ++f) {
            float xfv = __shfl(xv, (t & 32) | f);
            a += xfv * rc[f];
        }
        sum += fmaxf(a, 0.f);
        cnt += 1.f;
    }
    if (gcur >= 0) {
        atomicAdd(&pool[gcur * LATENT + l], sum);
        if (l == 0) atomicAdd(&pcnt[gcur], cnt);
    }
}

// ---------------- final FC ----------------
__global__ void final_kernel(const float* __restrict__ pool, const float* __restrict__ pcnt,
                             const float* __restrict__ fcw, const float* __restrict__ fcb,
                             float* __restrict__ out)
{
    int t = blockIdx.x * blockDim.x + threadIdx.x;
    int gr = t >> 7, j = t & 127;
    if (gr >= N_GRAPHS) return;
    float inv = 1.0f / fmaxf(pcnt[gr], 1.0f);
    float o = fcb[j];
    #pragma unroll 8
    for (int l = 0; l < LATENT; ++l) {
        float pv = fmaxf(pool[gr * LATENT + l] * inv, 0.0f);
        o += pv * fcw[l * EMBED + j];
    }
    out[gr * EMBED + j] = o;
}

extern "C" void kernel_launch(void* const* d_in, const int* in_sizes, int n_in,
                              void* d_out, int out_size, void* d_ws, size_t ws_size,
                              hipStream_t stream)
{
    const float* x     = (const float*)d_in[0];
    const int*   ei    = (const int*)d_in[1];
    const float* ea    = (const float*)d_in[2];
    const int*   batch = (const int*)d_in[3];
    const float* W1    = (const float*)d_in[4];
    const float* b1    = (const float*)d_in[5];
    const float* W2    = (const float*)d_in[6];
    const float* b2    = (const float*)d_in[7];
    const float* root  = (const float*)d_in[8];
    const float* cb    = (const float*)d_in[9];
    const float* fcw   = (const float*)d_in[10];
    const float* fcb   = (const float*)d_in[11];
    float* out = (float*)d_out;

    char* w = (char*)d_ws;
    auto alloc = [&](size_t bytes) {
        char* p = w;
        w += (bytes + 255) & ~size_t(255);
        return p;
    };
    ushort* W2T  = (ushort*)alloc((size_t)32 * KW * 2);
    __half* aggh = (__half*)alloc((size_t)N_NODES * LATENT * 2);
    float*  pool = (float*)alloc(N_GRAPHS * LATENT * 4);
    float*  pcnt = (float*)alloc(N_GRAPHS * 4);

    // 782 blocks x 256 = 200192 threads >= 200000 needed for agg zeroing
    prep_kernel<<<782, 256, 0, stream>>>(W2, b2, W2T, (uint4*)aggh, pool, pcnt);
    edge_mfma_kernel<<<N_EBLK, 512, 0, stream>>>(x, ei, ea, W1, b1, W2T, aggh);
    nodepool_kernel<<<(N_NODES + 8 * VN - 1) / (8 * VN), 256, 0, stream>>>(
        x, aggh, root, cb, batch, pool, pcnt);
    final_kernel<<<(N_GRAPHS * EMBED + 255) / 256, 256, 0, stream>>>(pool, pcnt, fcw, fcb, out);
}